// Round 4
// baseline (1545.197 us; speedup 1.0000x reference)
//
#include <hip/hip_runtime.h>
#include <hip/hip_bf16.h>

// MultiScaleRetention forward. Inputs/outputs FLOAT32; internals bf16 MFMA.
//   0) convert x -> xb (bf16); transpose weights f32 -> bf16
//   1) GEMM1: xb(4096,1024) @ Wt^T; epilogue: bias, k-scale, FUSED ROTARY
//      (f32 rotate via lane-pair shfl), split hi/lo bf16 q,k; vT bf16; g f32
//   2) retention: split-precision QK^T (3 MFMAs) * decay-mask -> PV (bf16 P),
//      rowsum denom, groupnorm(128) + silu(g f32) gating -> gated bf16
//   3) GEMM2: gated @ oT^T + o_b -> d_out (f32)
//
// R4 changes vs R3 (absmax 3.9e-2 -> target < 2.09e-2):
//   - rotary fused into GEMM1 epilogue: q,k rounded to bf16 ONCE (was twice)
//   - q,k stored as hi/lo bf16 pairs; QK^T = qh*kh + ql*kh + qh*kl (f32-class)
//   - g kept in f32 (only read elementwise; no MFMA needs it)

typedef __hip_bfloat16 bf16;
typedef short bf16x4 __attribute__((ext_vector_type(4)));
typedef short bf16x8 __attribute__((ext_vector_type(8)));
typedef float floatx4 __attribute__((ext_vector_type(4)));

#define B_SZ 2
#define SEQ 2048
#define NH 16
#define KD 64
#define HD 128

__device__ __forceinline__ float b2f(bf16 x) { return __bfloat162float(x); }
__device__ __forceinline__ bf16 f2b(float x) { return __float2bfloat16(x); }

// ---------------- f32 -> bf16 convert (x) ----------------
__global__ void convert_k(const float* __restrict__ in, bf16* __restrict__ out) {
  int i = blockIdx.x * 256 + threadIdx.x;  // one float4 per thread
  float4 v = reinterpret_cast<const float4*>(in)[i];
  union { bf16 h[4]; bf16x4 v4; } u;
  u.h[0] = f2b(v.x); u.h[1] = f2b(v.y); u.h[2] = f2b(v.z); u.h[3] = f2b(v.w);
  reinterpret_cast<bf16x4*>(out)[i] = u.v4;
}

// ---------------- weight transpose: in f32 (K,N) -> out bf16 (N,K) --------
__global__ void transpose_k(const float* __restrict__ in, bf16* __restrict__ out,
                            int K, int N) {
  __shared__ float tile[32][33];
  int tx = threadIdx.x, ty = threadIdx.y;
  int n0 = blockIdx.x * 32, k0 = blockIdx.y * 32;
#pragma unroll
  for (int j = 0; j < 4; ++j)
    tile[ty + j * 8][tx] = in[(size_t)(k0 + ty + j * 8) * N + n0 + tx];
  __syncthreads();
#pragma unroll
  for (int j = 0; j < 4; ++j)
    out[(size_t)(n0 + ty + j * 8) * K + k0 + tx] = f2b(tile[tx][ty + j * 8]);
}

// ---------------- GEMM: C(M,N) = A(M,K) @ Bt(N,K)^T ----------------
// MODE 0: QKVG epilogue (bias, k-scale, fused rotary, hi/lo split, routing)
// MODE 1: output projection epilogue (f32 bias + f32 store)
template <int BM, int BN, int MODE>
__global__ __launch_bounds__(256, 2) void gemm_bt(
    const bf16* __restrict__ A, const bf16* __restrict__ Bt, int Kdim, int Ndim,
    const float* __restrict__ bias_q, const float* __restrict__ bias_k,
    const float* __restrict__ bias_v, const float* __restrict__ bias_g,
    bf16* __restrict__ out_qh, bf16* __restrict__ out_ql,
    bf16* __restrict__ out_kh, bf16* __restrict__ out_kl,
    bf16* __restrict__ out_vT, float* __restrict__ out_g,
    float* __restrict__ outF) {
  __shared__ bf16 As[BM * 32];
  __shared__ bf16 Bs[BN * 32];
  const int tid = threadIdx.x;
  const int wave = tid >> 6, lane = tid & 63;
  const int quad = lane >> 4, l16 = lane & 15;
  const int m0 = blockIdx.y * BM, n0 = blockIdx.x * BN;
  constexpr int FI = BM / 32;
  constexpr int FJ = BN / 32;
  const int wm = (wave >> 1) * (BM / 2), wn = (wave & 1) * (BN / 2);

  floatx4 acc[FI][FJ] = {};

  for (int k0 = 0; k0 < Kdim; k0 += 32) {
    bf16x8 sa[BM / 64], sb[BN / 64];
#pragma unroll
    for (int j = 0; j < BM / 64; ++j) {
      int c = (j * 4 + wave) * 64 + lane;
      sa[j] = *(const bf16x8*)(A + (size_t)(m0 + (c >> 2)) * Kdim + k0 + (c & 3) * 8);
    }
#pragma unroll
    for (int j = 0; j < BN / 64; ++j) {
      int c = (j * 4 + wave) * 64 + lane;
      sb[j] = *(const bf16x8*)(Bt + (size_t)(n0 + (c >> 2)) * Kdim + k0 + (c & 3) * 8);
    }
#pragma unroll
    for (int j = 0; j < BM / 64; ++j) {
      int c = (j * 4 + wave) * 64 + lane;
      *(bf16x8*)&As[c * 8] = sa[j];
    }
#pragma unroll
    for (int j = 0; j < BN / 64; ++j) {
      int c = (j * 4 + wave) * 64 + lane;
      *(bf16x8*)&Bs[c * 8] = sb[j];
    }
    __syncthreads();

    bf16x8 af[FI], bfr[FJ];
#pragma unroll
    for (int i = 0; i < FI; ++i)
      af[i] = *(const bf16x8*)&As[(wm + i * 16 + l16) * 32 + quad * 8];
#pragma unroll
    for (int j = 0; j < FJ; ++j)
      bfr[j] = *(const bf16x8*)&Bs[(wn + j * 16 + l16) * 32 + quad * 8];
#pragma unroll
    for (int i = 0; i < FI; ++i)
#pragma unroll
      for (int j = 0; j < FJ; ++j)
        acc[i][j] = __builtin_amdgcn_mfma_f32_16x16x32_bf16(af[i], bfr[j],
                                                            acc[i][j], 0, 0, 0);
    __syncthreads();
  }

  // epilogue: C layout col=lane&15 (n), row=quad*4+r (m)
#pragma unroll
  for (int i = 0; i < FI; ++i) {
#pragma unroll
    for (int j = 0; j < FJ; ++j) {
#pragma unroll
      for (int r = 0; r < 4; ++r) {
        int gm = m0 + wm + i * 16 + quad * 4 + r;
        int gn = n0 + wn + j * 16 + l16;
        float v = acc[i][j][r];
        if (MODE == 1) {
          v += bias_q[gn];  // bias_q = o_b
          outF[(size_t)gm * Ndim + gn] = v;
        } else {
          int b = gm >> 11, s = gm & 2047;
          if (gn < 2048) {
            // q or k section: bias (+scale), then fused rotary in f32.
            bool is_k = gn >= 1024;
            int jj = is_k ? gn - 1024 : gn;
            v += is_k ? bias_k[jj] : bias_q[jj];
            if (is_k) v *= 0.125f;  // SCALING = KEY_DIM^-0.5
            int d = jj & 63;              // dim within head
            int ii = d >> 1;              // rotary pair index (0..31)
            // half[ii] = 10000^(-ii/31); ang = s * half[ii]
            float half = exp2f(-(float)ii * (13.287712379549449f / 31.0f));
            float ang = (float)s * half;
            float sn = sinf(ang), cs = cosf(ang);
            float vp = __shfl_xor(v, 1);  // partner col (gn parity = l16 parity)
            float vr = (d & 1) ? (v * cs + vp * sn)   // odd: x[2i+1]c + x[2i]s
                               : (v * cs - vp * sn);  // even: x[2i]c - x[2i+1]s
            bf16 hi = f2b(vr);
            bf16 lo = f2b(vr - b2f(hi));
            int h = jj >> 6;
            size_t idx = (((size_t)b * NH + h) * SEQ + s) * KD + d;
            if (is_k) { out_kh[idx] = hi; out_kl[idx] = lo; }
            else      { out_qh[idx] = hi; out_ql[idx] = lo; }
          } else if (gn < 4096) {
            int jj = gn - 2048;
            v += bias_v[jj];
            int h = jj >> 7, d = jj & 127;
            out_vT[(((size_t)b * NH + h) * HD + d) * SEQ + s] = f2b(v);
          } else {
            int jj = gn - 4096;
            v += bias_g[jj];
            out_g[(size_t)gm * 2048 + jj] = v;  // f32, no rounding
          }
        }
      }
    }
  }
}

// ---------------- retention core ----------------
// grid (S/64, NH, B), 4 waves/block; wave w owns rows [m0, m0+16).
// NOTE: waves have DIFFERENT trip counts (causal) -> per-wave lgkmcnt fence,
// NOT __syncthreads (would deadlock).
__global__ __launch_bounds__(256, 2) void retention_k(
    const bf16* __restrict__ qh, const bf16* __restrict__ ql,
    const bf16* __restrict__ kh, const bf16* __restrict__ kl,
    const bf16* __restrict__ vT, const float* __restrict__ g,
    bf16* __restrict__ gated) {
  __shared__ bf16 Pl[4][16 * 32];  // per-wave P tile (C-layout -> A-layout)
  const int wave = threadIdx.x >> 6, lane = threadIdx.x & 63;
  const int quad = lane >> 4, l16 = lane & 15;
  const int h = blockIdx.y, b = blockIdx.z;
  const int bh = b * NH + h;
  const int m0 = blockIdx.x * 64 + wave * 16;

  const float t = exp2f(-(float)(5 + h));  // 1-gamma (exact)
  const float lng = log1pf(-t);            // ln(gamma)
  const float log2g = lng * 1.44269504088896340736f;

  // masksum(m) = (1-gamma^(m+1))/(1-gamma); expm1 avoids cancellation
  float inv_ms[4];
#pragma unroll
  for (int r = 0; r < 4; ++r) {
    int m = m0 + quad * 4 + r;
    float num = -expm1f((float)(m + 1) * lng);
    inv_ms[r] = rsqrtf(num / t);
  }

  const size_t qoff = ((size_t)bh * SEQ + m0 + l16) * KD;
  bf16x8 aq0h = *(const bf16x8*)&qh[qoff + quad * 8];
  bf16x8 aq1h = *(const bf16x8*)&qh[qoff + 32 + quad * 8];
  bf16x8 aq0l = *(const bf16x8*)&ql[qoff + quad * 8];
  bf16x8 aq1l = *(const bf16x8*)&ql[qoff + 32 + quad * 8];

  floatx4 oacc[8] = {};
  float rowsum[4] = {0.f, 0.f, 0.f, 0.f};

  const bf16* khb = kh + (size_t)bh * SEQ * KD;
  const bf16* klb = kl + (size_t)bh * SEQ * KD;
  const bf16* vbase = vT + (size_t)bh * HD * SEQ;
  const int ntiles = (m0 >> 5) + 1;

  for (int nt = 0; nt < ntiles; ++nt) {
    const int n0 = nt * 32;
    floatx4 sc[2];
#pragma unroll
    for (int hh = 0; hh < 2; ++hh) {
      const size_t koff = (size_t)(n0 + hh * 16 + l16) * KD;
      bf16x8 bk0h = *(const bf16x8*)&khb[koff + quad * 8];
      bf16x8 bk1h = *(const bf16x8*)&khb[koff + 32 + quad * 8];
      bf16x8 bk0l = *(const bf16x8*)&klb[koff + quad * 8];
      bf16x8 bk1l = *(const bf16x8*)&klb[koff + 32 + quad * 8];
      floatx4 z = {0.f, 0.f, 0.f, 0.f};
      z = __builtin_amdgcn_mfma_f32_16x16x32_bf16(aq0h, bk0h, z, 0, 0, 0);
      z = __builtin_amdgcn_mfma_f32_16x16x32_bf16(aq1h, bk1h, z, 0, 0, 0);
      z = __builtin_amdgcn_mfma_f32_16x16x32_bf16(aq0l, bk0h, z, 0, 0, 0);
      z = __builtin_amdgcn_mfma_f32_16x16x32_bf16(aq1l, bk1h, z, 0, 0, 0);
      z = __builtin_amdgcn_mfma_f32_16x16x32_bf16(aq0h, bk0l, z, 0, 0, 0);
      z = __builtin_amdgcn_mfma_f32_16x16x32_bf16(aq1h, bk1l, z, 0, 0, 0);
      sc[hh] = z;
    }
    // decay mask + row-normalizer; row sums; stage P to LDS (A-layout xform)
#pragma unroll
    for (int hh = 0; hh < 2; ++hh) {
#pragma unroll
      for (int r = 0; r < 4; ++r) {
        int m = m0 + quad * 4 + r;
        int n = n0 + hh * 16 + l16;
        int diff = m - n;
        float p = 0.f;
        if (diff >= 0) p = sc[hh][r] * exp2f((float)diff * log2g) * inv_ms[r];
        rowsum[r] += p;
        Pl[wave][(quad * 4 + r) * 32 + hh * 16 + l16] = f2b(p);
      }
    }
    asm volatile("s_waitcnt lgkmcnt(0)" ::: "memory");
    bf16x8 pa = *(const bf16x8*)&Pl[wave][l16 * 32 + quad * 8];
#pragma unroll
    for (int dt = 0; dt < 8; ++dt) {
      const bf16* vrow = vbase + (size_t)(dt * 16 + l16) * SEQ + n0;
      bf16x8 bv = *(const bf16x8*)&vrow[quad * 8];
      oacc[dt] = __builtin_amdgcn_mfma_f32_16x16x32_bf16(pa, bv, oacc[dt], 0, 0, 0);
    }
  }

  // denom = clip(|row sum|, 1); groupnorm over 128 dims; silu gate
  float inv_den[4];
#pragma unroll
  for (int r = 0; r < 4; ++r) {
    float v = rowsum[r];
    v += __shfl_xor(v, 1);
    v += __shfl_xor(v, 2);
    v += __shfl_xor(v, 4);
    v += __shfl_xor(v, 8);
    inv_den[r] = 1.0f / fmaxf(fabsf(v), 1.0f);
  }
  float s1[4] = {}, s2[4] = {};
#pragma unroll
  for (int dt = 0; dt < 8; ++dt) {
#pragma unroll
    for (int r = 0; r < 4; ++r) {
      float v = oacc[dt][r] * inv_den[r];
      oacc[dt][r] = v;
      s1[r] += v;
      s2[r] += v * v;
    }
  }
  float mean[4], istd[4];
#pragma unroll
  for (int r = 0; r < 4; ++r) {
    float a = s1[r], q2 = s2[r];
    a += __shfl_xor(a, 1); a += __shfl_xor(a, 2);
    a += __shfl_xor(a, 4); a += __shfl_xor(a, 8);
    q2 += __shfl_xor(q2, 1); q2 += __shfl_xor(q2, 2);
    q2 += __shfl_xor(q2, 4); q2 += __shfl_xor(q2, 8);
    mean[r] = a * (1.0f / 128.0f);
    float var = q2 * (1.0f / 128.0f) - mean[r] * mean[r];
    istd[r] = rsqrtf(fmaxf(var, 0.0f) + 1e-5f);
  }
#pragma unroll
  for (int dt = 0; dt < 8; ++dt) {
#pragma unroll
    for (int r = 0; r < 4; ++r) {
      int m = m0 + quad * 4 + r;
      int col = h * HD + dt * 16 + l16;
      float v = (oacc[dt][r] - mean[r]) * istd[r];
      float gv = g[((size_t)b * SEQ + m) * 2048 + col];
      float sg = gv / (1.0f + expf(-gv));
      gated[((size_t)b * SEQ + m) * 2048 + col] = f2b(sg * v);
    }
  }
}

// ---------------- launch ----------------
extern "C" void kernel_launch(void* const* d_in, const int* in_sizes, int n_in,
                              void* d_out, int out_size, void* d_ws,
                              size_t ws_size, hipStream_t stream) {
  const float* x   = (const float*)d_in[0];
  const float* q_w = (const float*)d_in[1];
  const float* q_b = (const float*)d_in[2];
  const float* k_w = (const float*)d_in[3];
  const float* k_b = (const float*)d_in[4];
  const float* v_w = (const float*)d_in[5];
  const float* v_b = (const float*)d_in[6];
  const float* g_w = (const float*)d_in[7];
  const float* g_b = (const float*)d_in[8];
  const float* o_w = (const float*)d_in[9];
  const float* o_b = (const float*)d_in[10];

  char* ws = (char*)d_ws;
  bf16* Wt    = (bf16*)ws; ws += (size_t)6144 * 1024 * 2;
  bf16* oT    = (bf16*)ws; ws += (size_t)1024 * 2048 * 2;
  bf16* xb    = (bf16*)ws; ws += (size_t)4096 * 1024 * 2;
  bf16* qhb   = (bf16*)ws; ws += (size_t)32 * 2048 * 64 * 2;
  bf16* qlb   = (bf16*)ws; ws += (size_t)32 * 2048 * 64 * 2;
  bf16* khb   = (bf16*)ws; ws += (size_t)32 * 2048 * 64 * 2;
  bf16* klb   = (bf16*)ws; ws += (size_t)32 * 2048 * 64 * 2;
  bf16* vTb   = (bf16*)ws; ws += (size_t)32 * 128 * 2048 * 2;
  float* gbuf = (float*)ws; ws += (size_t)2 * 2048 * 2048 * 4;
  bf16* gated = (bf16*)ws; ws += (size_t)4096 * 2048 * 2;

  convert_k<<<(4096 * 1024 / 4) / 256, 256, 0, stream>>>(x, xb);

  dim3 tb(32, 8);
  transpose_k<<<dim3(1024 / 32, 1024 / 32), tb, 0, stream>>>(q_w, Wt, 1024, 1024);
  transpose_k<<<dim3(1024 / 32, 1024 / 32), tb, 0, stream>>>(k_w, Wt + (size_t)1024 * 1024, 1024, 1024);
  transpose_k<<<dim3(2048 / 32, 1024 / 32), tb, 0, stream>>>(v_w, Wt + (size_t)2048 * 1024, 1024, 2048);
  transpose_k<<<dim3(2048 / 32, 1024 / 32), tb, 0, stream>>>(g_w, Wt + (size_t)4096 * 1024, 1024, 2048);
  transpose_k<<<dim3(1024 / 32, 2048 / 32), tb, 0, stream>>>(o_w, oT, 2048, 1024);

  gemm_bt<128, 128, 0><<<dim3(6144 / 128, 4096 / 128), 256, 0, stream>>>(
      xb, Wt, 1024, 6144, q_b, k_b, v_b, g_b,
      qhb, qlb, khb, klb, vTb, gbuf, nullptr);

  retention_k<<<dim3(SEQ / 64, NH, B_SZ), 256, 0, stream>>>(
      qhb, qlb, khb, klb, vTb, gbuf, gated);

  gemm_bt<128, 64, 1><<<dim3(1024 / 64, 4096 / 128), 256, 0, stream>>>(
      gated, oT, 2048, 1024, o_b, nullptr, nullptr, nullptr,
      nullptr, nullptr, nullptr, nullptr, nullptr, nullptr, (float*)d_out);
}

// Round 5
// 705.720 us; speedup vs baseline: 2.1895x; 2.1895x over previous
//
#include <hip/hip_runtime.h>
#include <hip/hip_bf16.h>

// MultiScaleRetention forward. Inputs/outputs FLOAT32; internals bf16 MFMA.
//   0) convert x -> xb (bf16); transpose weights f32 -> bf16
//   1) GEMM1 (m97-style, global_load_lds staging): xb @ Wt^T; LEAN epilogue:
//      qk cols -> f32 Cqk (+bias,+k-scale); v -> vT bf16; g -> f32
//   2) router: rotary (f32) + hi/lo bf16 split + (bh,S,64) layout for q,k
//   3) retention: split-precision QK^T (6 MFMAs) * decay-mask -> PV (bf16 P),
//      rowsum denom, groupnorm(128) + silu(g f32) gating -> gated bf16
//   4) GEMM2: gated @ oT^T + o_b -> d_out (f32)
//
// R5 changes vs R4 (GEMM1 was 977us, 4.75GB traffic, VGPR=52 -> acc SPILLED
// to scratch; cause: 64x-unrolled epilogue w/ sincos+shfl kept acc live):
//   - GEMM1 epilogue stripped to plain stores (rotary moved to router kernel;
//     identical numerics: acc f32 -> Cqk f32 exact -> rotate -> one hi/lo round)
//   - staging restored to global_load_lds width=16 (m97 pattern; R1's NaN was
//     the f32-dtype bug, not this)
//   - Kdim is a template constant (exact m97 K-loop shape)

typedef __hip_bfloat16 bf16;
typedef short bf16x4 __attribute__((ext_vector_type(4)));
typedef short bf16x8 __attribute__((ext_vector_type(8)));
typedef float floatx4 __attribute__((ext_vector_type(4)));

#define B_SZ 2
#define SEQ 2048
#define NH 16
#define KD 64
#define HD 128

// global->LDS direct copy, 16B/lane. LDS dest is wave-uniform base + lane*16.
// Generic LDS pointers carry the AS3 offset in the low 32 bits.
#define ASYNC16(gp, lp)                                                             \
  __builtin_amdgcn_global_load_lds(                                                 \
      (const __attribute__((address_space(1))) unsigned int*)(unsigned long long)(const void*)(gp), \
      (__attribute__((address_space(3))) unsigned int*)(unsigned int)(unsigned long long)(void*)(lp), \
      16, 0, 0)

__device__ __forceinline__ float b2f(bf16 x) { return __bfloat162float(x); }
__device__ __forceinline__ bf16 f2b(float x) { return __float2bfloat16(x); }

// ---------------- f32 -> bf16 convert (x) ----------------
__global__ void convert_k(const float* __restrict__ in, bf16* __restrict__ out) {
  int i = blockIdx.x * 256 + threadIdx.x;  // one float4 per thread
  float4 v = reinterpret_cast<const float4*>(in)[i];
  union { bf16 h[4]; bf16x4 v4; } u;
  u.h[0] = f2b(v.x); u.h[1] = f2b(v.y); u.h[2] = f2b(v.z); u.h[3] = f2b(v.w);
  reinterpret_cast<bf16x4*>(out)[i] = u.v4;
}

// ---------------- weight transpose: in f32 (K,N) -> out bf16 (N,K) --------
__global__ void transpose_k(const float* __restrict__ in, bf16* __restrict__ out,
                            int K, int N) {
  __shared__ float tile[32][33];
  int tx = threadIdx.x, ty = threadIdx.y;
  int n0 = blockIdx.x * 32, k0 = blockIdx.y * 32;
#pragma unroll
  for (int j = 0; j < 4; ++j)
    tile[ty + j * 8][tx] = in[(size_t)(k0 + ty + j * 8) * N + n0 + tx];
  __syncthreads();
#pragma unroll
  for (int j = 0; j < 4; ++j)
    out[(size_t)(n0 + ty + j * 8) * K + k0 + tx] = f2b(tile[tx][ty + j * 8]);
}

// ---------------- GEMM: C(M,N) = A(M,K) @ Bt(N,K)^T ----------------
// MODE 0: QKVG epilogue (bias; qk -> f32 Cqk; v -> vT bf16; g -> f32)
// MODE 1: output projection epilogue (f32 bias + f32 store)
template <int BM, int BN, int KDIM, int MODE>
__global__ __launch_bounds__(256, 2) void gemm_bt(
    const bf16* __restrict__ A, const bf16* __restrict__ Bt, int Ndim,
    const float* __restrict__ bias_q, const float* __restrict__ bias_k,
    const float* __restrict__ bias_v, const float* __restrict__ bias_g,
    float* __restrict__ outCqk, bf16* __restrict__ out_vT,
    float* __restrict__ out_g, float* __restrict__ outF) {
  __shared__ bf16 As[BM * 32];
  __shared__ bf16 Bs[BN * 32];
  const int tid = threadIdx.x;
  const int wave = tid >> 6, lane = tid & 63;
  const int quad = lane >> 4, l16 = lane & 15;
  const int m0 = blockIdx.y * BM, n0 = blockIdx.x * BN;
  constexpr int FI = BM / 32;
  constexpr int FJ = BN / 32;
  const int wm = (wave >> 1) * (BM / 2), wn = (wave & 1) * (BN / 2);

  floatx4 acc[FI][FJ] = {};

  for (int k0 = 0; k0 < KDIM; k0 += 32) {
#pragma unroll
    for (int j = 0; j < BM / 64; ++j) {
      int cbase = (j * 4 + wave) * 64;
      int c = cbase + lane;
      const bf16* g = A + (size_t)(m0 + (c >> 2)) * KDIM + k0 + (c & 3) * 8;
      ASYNC16(g, &As[cbase * 8]);
    }
#pragma unroll
    for (int j = 0; j < BN / 64; ++j) {
      int cbase = (j * 4 + wave) * 64;
      int c = cbase + lane;
      const bf16* g = Bt + (size_t)(n0 + (c >> 2)) * KDIM + k0 + (c & 3) * 8;
      ASYNC16(g, &Bs[cbase * 8]);
    }
    __syncthreads();  // compiler drains vmcnt(0) before s_barrier

    bf16x8 af[FI], bfr[FJ];
#pragma unroll
    for (int i = 0; i < FI; ++i)
      af[i] = *(const bf16x8*)&As[(wm + i * 16 + l16) * 32 + quad * 8];
#pragma unroll
    for (int j = 0; j < FJ; ++j)
      bfr[j] = *(const bf16x8*)&Bs[(wn + j * 16 + l16) * 32 + quad * 8];
#pragma unroll
    for (int i = 0; i < FI; ++i)
#pragma unroll
      for (int j = 0; j < FJ; ++j)
        acc[i][j] = __builtin_amdgcn_mfma_f32_16x16x32_bf16(af[i], bfr[j],
                                                            acc[i][j], 0, 0, 0);
    __syncthreads();
  }

  // LEAN epilogue: C layout col=lane&15 (n), row=quad*4+r (m)
#pragma unroll
  for (int i = 0; i < FI; ++i) {
#pragma unroll
    for (int j = 0; j < FJ; ++j) {
#pragma unroll
      for (int r = 0; r < 4; ++r) {
        int gm = m0 + wm + i * 16 + quad * 4 + r;
        int gn = n0 + wn + j * 16 + l16;
        float v = acc[i][j][r];
        if (MODE == 1) {
          v += bias_q[gn];  // bias_q = o_b
          outF[(size_t)gm * Ndim + gn] = v;
        } else {
          int b = gm >> 11, s = gm & 2047;
          if (gn < 2048) {
            bool is_k = gn >= 1024;
            int jj = is_k ? gn - 1024 : gn;
            v += is_k ? bias_k[jj] : bias_q[jj];
            if (is_k) v *= 0.125f;  // SCALING = KEY_DIM^-0.5
            outCqk[(size_t)gm * 2048 + gn] = v;  // f32, exact
          } else if (gn < 4096) {
            int jj = gn - 2048;
            v += bias_v[jj];
            int h = jj >> 7, d = jj & 127;
            out_vT[(((size_t)b * NH + h) * HD + d) * SEQ + s] = f2b(v);
          } else {
            int jj = gn - 4096;
            v += bias_g[jj];
            out_g[(size_t)gm * 2048 + jj] = v;  // f32
          }
        }
      }
    }
  }
}

// ---------------- router: rotary + hi/lo split + layout ----------------
// one thread per rotary pair; Cqk (4096, 2048) f32: cols 0..1023 q, 1024.. k
__global__ void router_k(const float* __restrict__ Cqk,
                         bf16* __restrict__ qh, bf16* __restrict__ ql,
                         bf16* __restrict__ kh, bf16* __restrict__ kl) {
  int t = blockIdx.x * 256 + threadIdx.x;  // 4096*1024 threads
  int row = t >> 10, pc = t & 1023;
  int b = row >> 11, s = row & 2047;
  bool is_k = pc >= 512;
  int jj = (pc - (is_k ? 512 : 0)) * 2;  // even, 0..1022
  int h = jj >> 6, d = jj & 63, ii = d >> 1;
  float2 v = *(const float2*)&Cqk[(size_t)row * 2048 + pc * 2];
  // half[ii] = 10000^(-ii/31); ang = s * half[ii]
  float half = exp2f(-(float)ii * (13.287712379549449f / 31.0f));
  float ang = (float)s * half;
  float sn = sinf(ang), cs = cosf(ang);
  float e = v.x * cs - v.y * sn;   // even:  x[2i]c   - x[2i+1]s
  float o = v.y * cs + v.x * sn;   // odd:   x[2i+1]c + x[2i]s
  bf16 eh = f2b(e), oh = f2b(o);
  bf16 el = f2b(e - b2f(eh)), ol = f2b(o - b2f(oh));
  size_t idx = (((size_t)b * NH + h) * SEQ + s) * KD + d;  // d even -> 4B align
  bf16* ph = is_k ? kh : qh;
  bf16* pl = is_k ? kl : ql;
  union { bf16 h2[2]; unsigned u; } uh, ul;
  uh.h2[0] = eh; uh.h2[1] = oh;
  ul.h2[0] = el; ul.h2[1] = ol;
  *(unsigned*)&ph[idx] = uh.u;
  *(unsigned*)&pl[idx] = ul.u;
}

// ---------------- retention core ----------------
// grid (S/64, NH, B), 4 waves/block; wave w owns rows [m0, m0+16).
// NOTE: waves have DIFFERENT trip counts (causal) -> per-wave lgkmcnt fence,
// NOT __syncthreads (would deadlock).
__global__ __launch_bounds__(256, 2) void retention_k(
    const bf16* __restrict__ qh, const bf16* __restrict__ ql,
    const bf16* __restrict__ kh, const bf16* __restrict__ kl,
    const bf16* __restrict__ vT, const float* __restrict__ g,
    bf16* __restrict__ gated) {
  __shared__ bf16 Pl[4][16 * 32];  // per-wave P tile (C-layout -> A-layout)
  const int wave = threadIdx.x >> 6, lane = threadIdx.x & 63;
  const int quad = lane >> 4, l16 = lane & 15;
  const int h = blockIdx.y, b = blockIdx.z;
  const int bh = b * NH + h;
  const int m0 = blockIdx.x * 64 + wave * 16;

  const float t = exp2f(-(float)(5 + h));  // 1-gamma (exact)
  const float lng = log1pf(-t);            // ln(gamma)
  const float log2g = lng * 1.44269504088896340736f;

  // masksum(m) = (1-gamma^(m+1))/(1-gamma); expm1 avoids cancellation
  float inv_ms[4];
#pragma unroll
  for (int r = 0; r < 4; ++r) {
    int m = m0 + quad * 4 + r;
    float num = -expm1f((float)(m + 1) * lng);
    inv_ms[r] = rsqrtf(num / t);
  }

  const size_t qoff = ((size_t)bh * SEQ + m0 + l16) * KD;
  bf16x8 aq0h = *(const bf16x8*)&qh[qoff + quad * 8];
  bf16x8 aq1h = *(const bf16x8*)&qh[qoff + 32 + quad * 8];
  bf16x8 aq0l = *(const bf16x8*)&ql[qoff + quad * 8];
  bf16x8 aq1l = *(const bf16x8*)&ql[qoff + 32 + quad * 8];

  floatx4 oacc[8] = {};
  float rowsum[4] = {0.f, 0.f, 0.f, 0.f};

  const bf16* khb = kh + (size_t)bh * SEQ * KD;
  const bf16* klb = kl + (size_t)bh * SEQ * KD;
  const bf16* vbase = vT + (size_t)bh * HD * SEQ;
  const int ntiles = (m0 >> 5) + 1;

  for (int nt = 0; nt < ntiles; ++nt) {
    const int n0 = nt * 32;
    floatx4 sc[2];
#pragma unroll
    for (int hh = 0; hh < 2; ++hh) {
      const size_t koff = (size_t)(n0 + hh * 16 + l16) * KD;
      bf16x8 bk0h = *(const bf16x8*)&khb[koff + quad * 8];
      bf16x8 bk1h = *(const bf16x8*)&khb[koff + 32 + quad * 8];
      bf16x8 bk0l = *(const bf16x8*)&klb[koff + quad * 8];
      bf16x8 bk1l = *(const bf16x8*)&klb[koff + 32 + quad * 8];
      floatx4 z = {0.f, 0.f, 0.f, 0.f};
      z = __builtin_amdgcn_mfma_f32_16x16x32_bf16(aq0h, bk0h, z, 0, 0, 0);
      z = __builtin_amdgcn_mfma_f32_16x16x32_bf16(aq1h, bk1h, z, 0, 0, 0);
      z = __builtin_amdgcn_mfma_f32_16x16x32_bf16(aq0l, bk0h, z, 0, 0, 0);
      z = __builtin_amdgcn_mfma_f32_16x16x32_bf16(aq1l, bk1h, z, 0, 0, 0);
      z = __builtin_amdgcn_mfma_f32_16x16x32_bf16(aq0h, bk0l, z, 0, 0, 0);
      z = __builtin_amdgcn_mfma_f32_16x16x32_bf16(aq1h, bk1l, z, 0, 0, 0);
      sc[hh] = z;
    }
    // decay mask + row-normalizer; row sums; stage P to LDS (A-layout xform)
#pragma unroll
    for (int hh = 0; hh < 2; ++hh) {
#pragma unroll
      for (int r = 0; r < 4; ++r) {
        int m = m0 + quad * 4 + r;
        int n = n0 + hh * 16 + l16;
        int diff = m - n;
        float p = 0.f;
        if (diff >= 0) p = sc[hh][r] * exp2f((float)diff * log2g) * inv_ms[r];
        rowsum[r] += p;
        Pl[wave][(quad * 4 + r) * 32 + hh * 16 + l16] = f2b(p);
      }
    }
    asm volatile("s_waitcnt lgkmcnt(0)" ::: "memory");
    bf16x8 pa = *(const bf16x8*)&Pl[wave][l16 * 32 + quad * 8];
#pragma unroll
    for (int dt = 0; dt < 8; ++dt) {
      const bf16* vrow = vbase + (size_t)(dt * 16 + l16) * SEQ + n0;
      bf16x8 bv = *(const bf16x8*)&vrow[quad * 8];
      oacc[dt] = __builtin_amdgcn_mfma_f32_16x16x32_bf16(pa, bv, oacc[dt], 0, 0, 0);
    }
  }

  // denom = clip(|row sum|, 1); groupnorm over 128 dims; silu gate
  float inv_den[4];
#pragma unroll
  for (int r = 0; r < 4; ++r) {
    float v = rowsum[r];
    v += __shfl_xor(v, 1);
    v += __shfl_xor(v, 2);
    v += __shfl_xor(v, 4);
    v += __shfl_xor(v, 8);
    inv_den[r] = 1.0f / fmaxf(fabsf(v), 1.0f);
  }
  float s1[4] = {}, s2[4] = {};
#pragma unroll
  for (int dt = 0; dt < 8; ++dt) {
#pragma unroll
    for (int r = 0; r < 4; ++r) {
      float v = oacc[dt][r] * inv_den[r];
      oacc[dt][r] = v;
      s1[r] += v;
      s2[r] += v * v;
    }
  }
  float mean[4], istd[4];
#pragma unroll
  for (int r = 0; r < 4; ++r) {
    float a = s1[r], q2 = s2[r];
    a += __shfl_xor(a, 1); a += __shfl_xor(a, 2);
    a += __shfl_xor(a, 4); a += __shfl_xor(a, 8);
    q2 += __shfl_xor(q2, 1); q2 += __shfl_xor(q2, 2);
    q2 += __shfl_xor(q2, 4); q2 += __shfl_xor(q2, 8);
    mean[r] = a * (1.0f / 128.0f);
    float var = q2 * (1.0f / 128.0f) - mean[r] * mean[r];
    istd[r] = rsqrtf(fmaxf(var, 0.0f) + 1e-5f);
  }
#pragma unroll
  for (int dt = 0; dt < 8; ++dt) {
#pragma unroll
    for (int r = 0; r < 4; ++r) {
      int m = m0 + quad * 4 + r;
      int col = h * HD + dt * 16 + l16;
      float v = (oacc[dt][r] - mean[r]) * istd[r];
      float gv = g[((size_t)b * SEQ + m) * 2048 + col];
      float sg = gv / (1.0f + expf(-gv));
      gated[((size_t)b * SEQ + m) * 2048 + col] = f2b(sg * v);
    }
  }
}

// ---------------- launch ----------------
extern "C" void kernel_launch(void* const* d_in, const int* in_sizes, int n_in,
                              void* d_out, int out_size, void* d_ws,
                              size_t ws_size, hipStream_t stream) {
  const float* x   = (const float*)d_in[0];
  const float* q_w = (const float*)d_in[1];
  const float* q_b = (const float*)d_in[2];
  const float* k_w = (const float*)d_in[3];
  const float* k_b = (const float*)d_in[4];
  const float* v_w = (const float*)d_in[5];
  const float* v_b = (const float*)d_in[6];
  const float* g_w = (const float*)d_in[7];
  const float* g_b = (const float*)d_in[8];
  const float* o_w = (const float*)d_in[9];
  const float* o_b = (const float*)d_in[10];

  char* ws = (char*)d_ws;
  bf16* Wt    = (bf16*)ws; ws += (size_t)6144 * 1024 * 2;
  bf16* oT    = (bf16*)ws; ws += (size_t)1024 * 2048 * 2;
  bf16* xb    = (bf16*)ws; ws += (size_t)4096 * 1024 * 2;
  float* Cqk  = (float*)ws; ws += (size_t)4096 * 2048 * 4;
  bf16* qhb   = (bf16*)ws; ws += (size_t)32 * 2048 * 64 * 2;
  bf16* qlb   = (bf16*)ws; ws += (size_t)32 * 2048 * 64 * 2;
  bf16* khb   = (bf16*)ws; ws += (size_t)32 * 2048 * 64 * 2;
  bf16* klb   = (bf16*)ws; ws += (size_t)32 * 2048 * 64 * 2;
  bf16* vTb   = (bf16*)ws; ws += (size_t)32 * 128 * 2048 * 2;
  float* gbuf = (float*)ws; ws += (size_t)2 * 2048 * 2048 * 4;
  bf16* gated = (bf16*)ws; ws += (size_t)4096 * 2048 * 2;

  convert_k<<<(4096 * 1024 / 4) / 256, 256, 0, stream>>>(x, xb);

  dim3 tb(32, 8);
  transpose_k<<<dim3(1024 / 32, 1024 / 32), tb, 0, stream>>>(q_w, Wt, 1024, 1024);
  transpose_k<<<dim3(1024 / 32, 1024 / 32), tb, 0, stream>>>(k_w, Wt + (size_t)1024 * 1024, 1024, 1024);
  transpose_k<<<dim3(2048 / 32, 1024 / 32), tb, 0, stream>>>(v_w, Wt + (size_t)2048 * 1024, 1024, 2048);
  transpose_k<<<dim3(2048 / 32, 1024 / 32), tb, 0, stream>>>(g_w, Wt + (size_t)4096 * 1024, 1024, 2048);
  transpose_k<<<dim3(1024 / 32, 2048 / 32), tb, 0, stream>>>(o_w, oT, 2048, 1024);

  gemm_bt<128, 128, 1024, 0><<<dim3(6144 / 128, 4096 / 128), 256, 0, stream>>>(
      xb, Wt, 6144, q_b, k_b, v_b, g_b, Cqk, vTb, gbuf, nullptr);

  router_k<<<(4096 * 1024) / 256, 256, 0, stream>>>(Cqk, qhb, qlb, khb, klb);

  retention_k<<<dim3(SEQ / 64, NH, B_SZ), 256, 0, stream>>>(
      qhb, qlb, khb, klb, vTb, gbuf, gated);

  gemm_bt<128, 64, 2048, 1><<<dim3(1024 / 64, 4096 / 128), 256, 0, stream>>>(
      gated, oT, 1024, o_b, nullptr, nullptr, nullptr, nullptr, nullptr,
      nullptr, (float*)d_out);
}